// Round 2
// baseline (1433.972 us; speedup 1.0000x reference)
//
#include <hip/hip_runtime.h>

#define RES 64
#define R3  (RES*RES*RES)
#define BB  8
#define CC  32
#define NN  65536
#define NORM_EPS 1e-8f

// ws layout:
//   uint   ws[0]            : norm_max bits (atomicMax target, init 0)
//   float  ws_f[16..39]     : mins[b*3+axis]
//   offset 4096 bytes       : uint counts[B*R3]  (8.4 MB)

__global__ void k_min(const float* __restrict__ pts, float* __restrict__ mins) {
    int ba = blockIdx.x;               // 0..23  => (b, axis)
    const float* p = pts + (size_t)ba * NN;
    float m = 1e30f;
    for (int i = threadIdx.x; i < NN; i += blockDim.x) m = fminf(m, p[i]);
    __shared__ float red[256];
    red[threadIdx.x] = m; __syncthreads();
    for (int s = 128; s > 0; s >>= 1) {
        if (threadIdx.x < s) red[threadIdx.x] = fminf(red[threadIdx.x], red[threadIdx.x + s]);
        __syncthreads();
    }
    if (threadIdx.x == 0) mins[ba] = red[0];
}

__global__ void k_normmax(const float* __restrict__ pts, const float* __restrict__ mins,
                          unsigned* __restrict__ nm) {
    int i = blockIdx.x * blockDim.x + threadIdx.x;   // over B*N
    int b = i / NN, n = i % NN;
    const float* p = pts + (size_t)b * 3 * NN + n;
    float x = __fsub_rn(p[0],        mins[b*3+0]);
    float y = __fsub_rn(p[NN],       mins[b*3+1]);
    float z = __fsub_rn(p[2*NN],     mins[b*3+2]);
    // ((x^2 + y^2) + z^2), plain rn ops, no FMA contraction
    float s = __fadd_rn(__fadd_rn(__fmul_rn(x, x), __fmul_rn(y, y)), __fmul_rn(z, z));
    float m = __fsqrt_rn(s);
    __shared__ float red[256];
    red[threadIdx.x] = m; __syncthreads();
    for (int st = 128; st > 0; st >>= 1) {
        if (threadIdx.x < st) red[threadIdx.x] = fmaxf(red[threadIdx.x], red[threadIdx.x + st]);
        __syncthreads();
    }
    if (threadIdx.x == 0) atomicMax(nm, __float_as_uint(red[0]));  // norms >= 0
}

__global__ void k_scatter(const float* __restrict__ pts, const float* __restrict__ feat,
                          const float* __restrict__ mins, const unsigned* __restrict__ nm,
                          unsigned* __restrict__ counts, float* __restrict__ out) {
    int i = blockIdx.x * blockDim.x + threadIdx.x;   // over B*N
    int b = i / NN, n = i % NN;
    float denom = __fadd_rn(__uint_as_float(*nm), NORM_EPS);
    // XLA rewrites divide(A, broadcast(scalar)) -> multiply(A, broadcast(1/scalar)).
    float inv = __fdiv_rn(1.0f, denom);
    const float* p = pts + (size_t)b * 3 * NN + n;
    float x = __fsub_rn(p[0],    mins[b*3+0]);
    float y = __fsub_rn(p[NN],   mins[b*3+1]);
    float z = __fsub_rn(p[2*NN], mins[b*3+2]);
    int ix = (int)(__fmul_rn(__fmul_rn(x, inv), 63.0f));
    int iy = (int)(__fmul_rn(__fmul_rn(y, inv), 63.0f));
    int iz = (int)(__fmul_rn(__fmul_rn(z, inv), 63.0f));
    ix = min(max(ix, 0), RES - 1);
    iy = min(max(iy, 0), RES - 1);
    iz = min(max(iz, 0), RES - 1);
    int vox = ix + iy * RES + iz * RES * RES;
    atomicAdd(&counts[(size_t)b * R3 + vox], 1u);
    const float* f = feat + (size_t)b * CC * NN + n;
    float* o = out + (size_t)b * CC * R3 + vox;
    #pragma unroll
    for (int c = 0; c < CC; c++) {
        atomicAdd(o + (size_t)c * R3, f[(size_t)c * NN]);
    }
}

__global__ void k_div(float* __restrict__ out, const unsigned* __restrict__ counts) {
    size_t i = (size_t)blockIdx.x * blockDim.x + threadIdx.x;   // over B*C*R3
    int vox = (int)(i % R3);
    int bc  = (int)(i / R3);
    int b   = bc / CC;
    float cnt = (float)counts[(size_t)b * R3 + vox];
    out[i] = out[i] / fmaxf(cnt, 1.0f);
}

extern "C" void kernel_launch(void* const* d_in, const int* in_sizes, int n_in,
                              void* d_out, int out_size, void* d_ws, size_t ws_size,
                              hipStream_t stream) {
    const float* pts  = (const float*)d_in[0];
    const float* feat = (const float*)d_in[1];
    float* out = (float*)d_out;

    unsigned* nm     = (unsigned*)d_ws;
    float*    mins   = (float*)d_ws + 16;
    unsigned* counts = (unsigned*)((char*)d_ws + 4096);

    hipMemsetAsync(d_out, 0, (size_t)out_size * sizeof(float), stream);
    hipMemsetAsync(d_ws, 0, 4096 + (size_t)BB * R3 * sizeof(unsigned), stream);

    k_min<<<BB * 3, 256, 0, stream>>>(pts, mins);
    k_normmax<<<(BB * NN) / 256, 256, 0, stream>>>(pts, mins, nm);
    k_scatter<<<(BB * NN) / 256, 256, 0, stream>>>(pts, feat, mins, nm, counts, out);
    k_div<<<((size_t)BB * CC * R3) / 256, 256, 0, stream>>>(out, counts);
}

// Round 3
// 561.951 us; speedup vs baseline: 2.5518x; 2.5518x over previous
//
#include <hip/hip_runtime.h>

#define RES 64
#define R3  (RES*RES*RES)        // 262144
#define BB  8
#define CC  32
#define NN  65536
#define NBINS (BB*R3)            // 2097152
#define NPTS  (BB*NN)            // 524288
#define NORM_EPS 1e-8f

#define SCAN_BLK 1024
#define NBLK (NBINS/SCAN_BLK)    // 2048

// ws layout (byte offsets). total ~87.4 MB
#define OFF_COUNTS  4096
#define OFF_OFFSETS (OFF_COUNTS  + NBINS*4)
#define OFF_TOTALS  (OFF_OFFSETS + NBINS*4)
#define OFF_VOX     (OFF_TOTALS  + 65536)
#define OFF_ORDER   (OFF_VOX     + NPTS*4)
#define OFF_FEATT   (OFF_ORDER   + NPTS*4)

__global__ void k_min(const float* __restrict__ pts, float* __restrict__ mins) {
    int ba = blockIdx.x;               // 0..23  => (b, axis)
    const float* p = pts + (size_t)ba * NN;
    float m = 1e30f;
    for (int i = threadIdx.x; i < NN; i += blockDim.x) m = fminf(m, p[i]);
    __shared__ float red[256];
    red[threadIdx.x] = m; __syncthreads();
    for (int s = 128; s > 0; s >>= 1) {
        if (threadIdx.x < s) red[threadIdx.x] = fminf(red[threadIdx.x], red[threadIdx.x + s]);
        __syncthreads();
    }
    if (threadIdx.x == 0) mins[ba] = red[0];
}

__global__ void k_normmax(const float* __restrict__ pts, const float* __restrict__ mins,
                          unsigned* __restrict__ nm) {
    int i = blockIdx.x * blockDim.x + threadIdx.x;   // over B*N
    int b = i >> 16, n = i & (NN - 1);
    const float* p = pts + (size_t)b * 3 * NN + n;
    float x = __fsub_rn(p[0],        mins[b*3+0]);
    float y = __fsub_rn(p[NN],       mins[b*3+1]);
    float z = __fsub_rn(p[2*NN],     mins[b*3+2]);
    float s = __fadd_rn(__fadd_rn(__fmul_rn(x, x), __fmul_rn(y, y)), __fmul_rn(z, z));
    float m = __fsqrt_rn(s);
    __shared__ float red[256];
    red[threadIdx.x] = m; __syncthreads();
    for (int st = 128; st > 0; st >>= 1) {
        if (threadIdx.x < st) red[threadIdx.x] = fmaxf(red[threadIdx.x], red[threadIdx.x + st]);
        __syncthreads();
    }
    if (threadIdx.x == 0) atomicMax(nm, __float_as_uint(red[0]));  // norms >= 0
}

// feat [B,C,N] -> featT [B,N,C], 32x32 tiles via LDS
__global__ void k_transpose(const float* __restrict__ feat, float* __restrict__ featT) {
    __shared__ float tile[32][33];
    int blk = blockIdx.x;                  // b*(NN/32) + ntile
    int b  = blk >> 11;                    // NN/32 = 2048
    int n0 = (blk & 2047) << 5;
    int tx = threadIdx.x & 31, ty = threadIdx.x >> 5;   // ty in 0..7
    const float* src = feat + (size_t)b * CC * NN;
    #pragma unroll
    for (int cc = 0; cc < 32; cc += 8)
        tile[cc + ty][tx] = src[(size_t)(cc + ty) * NN + n0 + tx];
    __syncthreads();
    float* dst = featT + ((size_t)b * NN + n0) * CC;
    #pragma unroll
    for (int nn = 0; nn < 32; nn += 8)
        dst[(size_t)(nn + ty) * CC + tx] = tile[tx][nn + ty];
}

__global__ void k_voxid(const float* __restrict__ pts, const float* __restrict__ mins,
                        const unsigned* __restrict__ nm,
                        unsigned* __restrict__ voxid, unsigned* __restrict__ counts) {
    int i = blockIdx.x * blockDim.x + threadIdx.x;   // over B*N
    int b = i >> 16, n = i & (NN - 1);
    float denom = __fadd_rn(__uint_as_float(*nm), NORM_EPS);
    float inv = __fdiv_rn(1.0f, denom);              // XLA: divide -> mul by reciprocal
    const float* p = pts + (size_t)b * 3 * NN + n;
    float x = __fsub_rn(p[0],    mins[b*3+0]);
    float y = __fsub_rn(p[NN],   mins[b*3+1]);
    float z = __fsub_rn(p[2*NN], mins[b*3+2]);
    int ix = (int)(__fmul_rn(__fmul_rn(x, inv), 63.0f));
    int iy = (int)(__fmul_rn(__fmul_rn(y, inv), 63.0f));
    int iz = (int)(__fmul_rn(__fmul_rn(z, inv), 63.0f));
    ix = min(max(ix, 0), RES - 1);
    iy = min(max(iy, 0), RES - 1);
    iz = min(max(iz, 0), RES - 1);
    unsigned vox = (unsigned)(ix + iy * RES + iz * RES * RES);
    voxid[i] = vox;
    atomicAdd(&counts[(size_t)b * R3 + vox], 1u);
}

__global__ void k_scansum(const unsigned* __restrict__ counts, unsigned* __restrict__ totals) {
    int blk = blockIdx.x, t = threadIdx.x;
    const unsigned* p = counts + (size_t)blk * SCAN_BLK;
    unsigned s = 0;
    #pragma unroll
    for (int j = 0; j < 4; j++) s += p[t + 256 * j];
    __shared__ unsigned red[256];
    red[t] = s; __syncthreads();
    for (int st = 128; st > 0; st >>= 1) {
        if (t < st) red[t] += red[t + st];
        __syncthreads();
    }
    if (t == 0) totals[blk] = red[0];
}

__global__ void k_scantop(unsigned* __restrict__ totals) {
    __shared__ unsigned red[256];
    int t = threadIdx.x;
    unsigned v[8], s = 0;
    #pragma unroll
    for (int j = 0; j < 8; j++) { v[j] = totals[t * 8 + j]; s += v[j]; }
    red[t] = s; __syncthreads();
    for (int st = 1; st < 256; st <<= 1) {
        unsigned tmp = (t >= st) ? red[t - st] : 0u;
        __syncthreads();
        red[t] += tmp;
        __syncthreads();
    }
    unsigned acc = (t == 0) ? 0u : red[t - 1];       // exclusive base
    #pragma unroll
    for (int j = 0; j < 8; j++) { totals[t * 8 + j] = acc; acc += v[j]; }
}

__global__ void k_scanfinal(const unsigned* __restrict__ counts,
                            const unsigned* __restrict__ totals,
                            unsigned* __restrict__ offsets) {
    __shared__ unsigned red[256];
    int blk = blockIdx.x, t = threadIdx.x;
    const unsigned* p = counts + (size_t)blk * SCAN_BLK;
    unsigned v[4], s = 0;
    #pragma unroll
    for (int j = 0; j < 4; j++) { v[j] = p[t * 4 + j]; s += v[j]; }
    red[t] = s; __syncthreads();
    for (int st = 1; st < 256; st <<= 1) {
        unsigned tmp = (t >= st) ? red[t - st] : 0u;
        __syncthreads();
        red[t] += tmp;
        __syncthreads();
    }
    unsigned acc = totals[blk] + ((t == 0) ? 0u : red[t - 1]);
    unsigned* q = offsets + (size_t)blk * SCAN_BLK;
    #pragma unroll
    for (int j = 0; j < 4; j++) { q[t * 4 + j] = acc; acc += v[j]; }
}

__global__ void k_fill(const unsigned* __restrict__ voxid, unsigned* __restrict__ offsets,
                       unsigned* __restrict__ order) {
    int i = blockIdx.x * blockDim.x + threadIdx.x;   // over B*N
    int b = i >> 16;
    unsigned bin = (unsigned)b * R3 + voxid[i];
    unsigned pos = atomicAdd(&offsets[bin], 1u);     // offsets becomes end-pointer
    order[pos] = (unsigned)i;
}

__global__ void k_accum(const unsigned* __restrict__ counts, const unsigned* __restrict__ offsets,
                        const unsigned* __restrict__ order, const float* __restrict__ featT,
                        float* __restrict__ out) {
    int bin = blockIdx.x * blockDim.x + threadIdx.x; // over NBINS
    int b   = bin >> 18;                             // R3 = 2^18
    int vox = bin & (R3 - 1);
    unsigned cnt   = counts[bin];
    unsigned end   = offsets[bin];                   // post-fill end pointer
    unsigned start = end - cnt;
    float acc[CC];
    #pragma unroll
    for (int c = 0; c < CC; c++) acc[c] = 0.f;
    for (unsigned k = start; k < end; k++) {
        unsigned i = order[k];
        const float* ft = featT + (size_t)i * CC;    // 128B contiguous per point
        #pragma unroll
        for (int c = 0; c < CC; c++) acc[c] += ft[c];
    }
    float inv = __fdiv_rn(1.0f, fmaxf((float)cnt, 1.0f));
    float* o = out + (size_t)b * CC * R3 + vox;
    #pragma unroll
    for (int c = 0; c < CC; c++) o[(size_t)c * R3] = __fmul_rn(acc[c], inv);
}

extern "C" void kernel_launch(void* const* d_in, const int* in_sizes, int n_in,
                              void* d_out, int out_size, void* d_ws, size_t ws_size,
                              hipStream_t stream) {
    const float* pts  = (const float*)d_in[0];
    const float* feat = (const float*)d_in[1];
    float* out = (float*)d_out;

    char* ws = (char*)d_ws;
    unsigned* nm      = (unsigned*)ws;
    float*    mins    = (float*)ws + 16;
    unsigned* counts  = (unsigned*)(ws + OFF_COUNTS);
    unsigned* offsets = (unsigned*)(ws + OFF_OFFSETS);
    unsigned* totals  = (unsigned*)(ws + OFF_TOTALS);
    unsigned* voxid   = (unsigned*)(ws + OFF_VOX);
    unsigned* order   = (unsigned*)(ws + OFF_ORDER);
    float*    featT   = (float*)(ws + OFF_FEATT);

    // zero header + counts in one shot
    hipMemsetAsync(d_ws, 0, OFF_COUNTS + (size_t)NBINS * 4, stream);

    k_min      <<<BB * 3,           256, 0, stream>>>(pts, mins);
    k_normmax  <<<NPTS / 256,       256, 0, stream>>>(pts, mins, nm);
    k_transpose<<<BB * (NN / 32),   256, 0, stream>>>(feat, featT);
    k_voxid    <<<NPTS / 256,       256, 0, stream>>>(pts, mins, nm, voxid, counts);
    k_scansum  <<<NBLK,             256, 0, stream>>>(counts, totals);
    k_scantop  <<<1,                256, 0, stream>>>(totals);
    k_scanfinal<<<NBLK,             256, 0, stream>>>(counts, totals, offsets);
    k_fill     <<<NPTS / 256,       256, 0, stream>>>(voxid, offsets, order);
    k_accum    <<<NBINS / 256,      256, 0, stream>>>(counts, offsets, order, featT, out);
}

// Round 4
// 478.950 us; speedup vs baseline: 2.9940x; 1.1733x over previous
//
#include <hip/hip_runtime.h>

#define RES 64
#define R3  (RES*RES*RES)        // 262144
#define BB  8
#define CC  32
#define NN  65536
#define NBINS (BB*R3)            // 2097152
#define NPTS  (BB*NN)            // 524288
#define NORM_EPS 1e-8f

#define SCAN_BLK 1024
#define NBLK (NBINS/SCAN_BLK)    // 2048

// ws layout (byte offsets). total ~87.4 MB
#define OFF_COUNTS  4096
#define OFF_OFFSETS (OFF_COUNTS  + NBINS*4)
#define OFF_TOTALS  (OFF_OFFSETS + NBINS*4)
#define OFF_VOX     (OFF_TOTALS  + 65536)
#define OFF_ORDER   (OFF_VOX     + NPTS*4)
#define OFF_FEATT   (OFF_ORDER   + NPTS*4)

__global__ __launch_bounds__(1024) void k_min(const float* __restrict__ pts, float* __restrict__ mins) {
    int ba = blockIdx.x;               // 0..23  => (b, axis)
    const float* p = pts + (size_t)ba * NN;
    float m = 1e30f;
    for (int i = threadIdx.x; i < NN; i += 1024) m = fminf(m, p[i]);
    __shared__ float red[1024];
    red[threadIdx.x] = m; __syncthreads();
    for (int s = 512; s > 0; s >>= 1) {
        if (threadIdx.x < s) red[threadIdx.x] = fminf(red[threadIdx.x], red[threadIdx.x + s]);
        __syncthreads();
    }
    if (threadIdx.x == 0) mins[ba] = red[0];
}

__global__ void k_normmax(const float* __restrict__ pts, const float* __restrict__ mins,
                          unsigned* __restrict__ nm) {
    int i = blockIdx.x * blockDim.x + threadIdx.x;   // over B*N
    int b = i >> 16, n = i & (NN - 1);
    const float* p = pts + (size_t)b * 3 * NN + n;
    float x = __fsub_rn(p[0],        mins[b*3+0]);
    float y = __fsub_rn(p[NN],       mins[b*3+1]);
    float z = __fsub_rn(p[2*NN],     mins[b*3+2]);
    float s = __fadd_rn(__fadd_rn(__fmul_rn(x, x), __fmul_rn(y, y)), __fmul_rn(z, z));
    float m = __fsqrt_rn(s);
    __shared__ float red[256];
    red[threadIdx.x] = m; __syncthreads();
    for (int st = 128; st > 0; st >>= 1) {
        if (threadIdx.x < st) red[threadIdx.x] = fmaxf(red[threadIdx.x], red[threadIdx.x + st]);
        __syncthreads();
    }
    if (threadIdx.x == 0) atomicMax(nm, __float_as_uint(red[0]));  // norms >= 0
}

// feat [B,C,N] -> featT [B,N,C], 32x32 tiles via LDS
__global__ void k_transpose(const float* __restrict__ feat, float* __restrict__ featT) {
    __shared__ float tile[32][33];
    int blk = blockIdx.x;                  // b*(NN/32) + ntile
    int b  = blk >> 11;                    // NN/32 = 2048
    int n0 = (blk & 2047) << 5;
    int tx = threadIdx.x & 31, ty = threadIdx.x >> 5;   // ty in 0..7
    const float* src = feat + (size_t)b * CC * NN;
    #pragma unroll
    for (int cc = 0; cc < 32; cc += 8)
        tile[cc + ty][tx] = src[(size_t)(cc + ty) * NN + n0 + tx];
    __syncthreads();
    float* dst = featT + ((size_t)b * NN + n0) * CC;
    #pragma unroll
    for (int nn = 0; nn < 32; nn += 8)
        dst[(size_t)(nn + ty) * CC + tx] = tile[tx][nn + ty];
}

__global__ void k_voxid(const float* __restrict__ pts, const float* __restrict__ mins,
                        const unsigned* __restrict__ nm,
                        unsigned* __restrict__ voxid, unsigned* __restrict__ counts) {
    int i = blockIdx.x * blockDim.x + threadIdx.x;   // over B*N
    int b = i >> 16, n = i & (NN - 1);
    float denom = __fadd_rn(__uint_as_float(*nm), NORM_EPS);
    float inv = __fdiv_rn(1.0f, denom);              // XLA: divide -> mul by reciprocal
    const float* p = pts + (size_t)b * 3 * NN + n;
    float x = __fsub_rn(p[0],    mins[b*3+0]);
    float y = __fsub_rn(p[NN],   mins[b*3+1]);
    float z = __fsub_rn(p[2*NN], mins[b*3+2]);
    int ix = (int)(__fmul_rn(__fmul_rn(x, inv), 63.0f));
    int iy = (int)(__fmul_rn(__fmul_rn(y, inv), 63.0f));
    int iz = (int)(__fmul_rn(__fmul_rn(z, inv), 63.0f));
    ix = min(max(ix, 0), RES - 1);
    iy = min(max(iy, 0), RES - 1);
    iz = min(max(iz, 0), RES - 1);
    unsigned vox = (unsigned)(ix + iy * RES + iz * RES * RES);
    voxid[i] = vox;
    atomicAdd(&counts[(size_t)b * R3 + vox], 1u);
}

__global__ void k_scansum(const unsigned* __restrict__ counts, unsigned* __restrict__ totals) {
    int blk = blockIdx.x, t = threadIdx.x;
    const unsigned* p = counts + (size_t)blk * SCAN_BLK;
    unsigned s = 0;
    #pragma unroll
    for (int j = 0; j < 4; j++) s += p[t + 256 * j];
    __shared__ unsigned red[256];
    red[t] = s; __syncthreads();
    for (int st = 128; st > 0; st >>= 1) {
        if (t < st) red[t] += red[t + st];
        __syncthreads();
    }
    if (t == 0) totals[blk] = red[0];
}

__global__ void k_scantop(unsigned* __restrict__ totals) {
    __shared__ unsigned red[256];
    int t = threadIdx.x;
    unsigned v[8], s = 0;
    #pragma unroll
    for (int j = 0; j < 8; j++) { v[j] = totals[t * 8 + j]; s += v[j]; }
    red[t] = s; __syncthreads();
    for (int st = 1; st < 256; st <<= 1) {
        unsigned tmp = (t >= st) ? red[t - st] : 0u;
        __syncthreads();
        red[t] += tmp;
        __syncthreads();
    }
    unsigned acc = (t == 0) ? 0u : red[t - 1];       // exclusive base
    #pragma unroll
    for (int j = 0; j < 8; j++) { totals[t * 8 + j] = acc; acc += v[j]; }
}

__global__ void k_scanfinal(const unsigned* __restrict__ counts,
                            const unsigned* __restrict__ totals,
                            unsigned* __restrict__ offsets) {
    __shared__ unsigned red[256];
    int blk = blockIdx.x, t = threadIdx.x;
    const unsigned* p = counts + (size_t)blk * SCAN_BLK;
    unsigned v[4], s = 0;
    #pragma unroll
    for (int j = 0; j < 4; j++) { v[j] = p[t * 4 + j]; s += v[j]; }
    red[t] = s; __syncthreads();
    for (int st = 1; st < 256; st <<= 1) {
        unsigned tmp = (t >= st) ? red[t - st] : 0u;
        __syncthreads();
        red[t] += tmp;
        __syncthreads();
    }
    unsigned acc = totals[blk] + ((t == 0) ? 0u : red[t - 1]);
    unsigned* q = offsets + (size_t)blk * SCAN_BLK;
    #pragma unroll
    for (int j = 0; j < 4; j++) { q[t * 4 + j] = acc; acc += v[j]; }
}

__global__ void k_fill(const unsigned* __restrict__ voxid, unsigned* __restrict__ offsets,
                       unsigned* __restrict__ order) {
    int i = blockIdx.x * blockDim.x + threadIdx.x;   // over B*N
    int b = i >> 16;
    unsigned bin = (unsigned)b * R3 + voxid[i];
    unsigned pos = atomicAdd(&offsets[bin], 1u);     // offsets becomes end-pointer
    order[pos] = (unsigned)i;
}

__global__ __launch_bounds__(256) void k_accum(
        const unsigned* __restrict__ counts, const unsigned* __restrict__ offsets,
        const unsigned* __restrict__ order, const float* __restrict__ featT,
        float* __restrict__ out) {
    __shared__ float tile[CC][260];                  // +4 pad
    int tid = threadIdx.x;
    int bin0 = blockIdx.x << 8;                      // 256 consecutive bins, same b
    int bin  = bin0 + tid;
    int b    = bin >> 18;                            // R3 = 2^18
    unsigned cnt   = counts[bin];
    unsigned end   = offsets[bin];                   // post-fill end pointer
    unsigned start = end - cnt;
    float acc[CC];
    #pragma unroll
    for (int c = 0; c < CC; c++) acc[c] = 0.f;
    for (unsigned k = start; k < end; k++) {
        unsigned i = order[k];
        const float4* ft = (const float4*)(featT + (size_t)i * CC);  // 128B aligned
        #pragma unroll
        for (int q = 0; q < CC / 4; q++) {
            float4 v = ft[q];
            acc[q*4+0] += v.x; acc[q*4+1] += v.y; acc[q*4+2] += v.z; acc[q*4+3] += v.w;
        }
    }
    float inv = __fdiv_rn(1.0f, fmaxf((float)cnt, 1.0f));
    #pragma unroll
    for (int c = 0; c < CC; c++) tile[c][tid] = __fmul_rn(acc[c], inv);
    __syncthreads();
    // transposed write: 1KB contiguous float4 rows per channel
    int vox0 = bin0 & (R3 - 1);
    float* ob = out + (size_t)b * CC * R3 + vox0;
    int lane64 = tid & 63;
    int crow   = tid >> 6;                            // 0..3
    #pragma unroll
    for (int cc = 0; cc < CC; cc += 4) {
        int c = cc + crow;
        float4 v = make_float4(tile[c][lane64*4+0], tile[c][lane64*4+1],
                               tile[c][lane64*4+2], tile[c][lane64*4+3]);
        *(float4*)(ob + (size_t)c * R3 + lane64*4) = v;
    }
}

extern "C" void kernel_launch(void* const* d_in, const int* in_sizes, int n_in,
                              void* d_out, int out_size, void* d_ws, size_t ws_size,
                              hipStream_t stream) {
    const float* pts  = (const float*)d_in[0];
    const float* feat = (const float*)d_in[1];
    float* out = (float*)d_out;

    char* ws = (char*)d_ws;
    unsigned* nm      = (unsigned*)ws;
    float*    mins    = (float*)ws + 16;
    unsigned* counts  = (unsigned*)(ws + OFF_COUNTS);
    unsigned* offsets = (unsigned*)(ws + OFF_OFFSETS);
    unsigned* totals  = (unsigned*)(ws + OFF_TOTALS);
    unsigned* voxid   = (unsigned*)(ws + OFF_VOX);
    unsigned* order   = (unsigned*)(ws + OFF_ORDER);
    float*    featT   = (float*)(ws + OFF_FEATT);

    hipMemsetAsync(d_ws, 0, OFF_COUNTS + (size_t)NBINS * 4, stream);

    k_min      <<<BB * 3,           1024, 0, stream>>>(pts, mins);
    k_normmax  <<<NPTS / 256,       256,  0, stream>>>(pts, mins, nm);
    k_transpose<<<BB * (NN / 32),   256,  0, stream>>>(feat, featT);
    k_voxid    <<<NPTS / 256,       256,  0, stream>>>(pts, mins, nm, voxid, counts);
    k_scansum  <<<NBLK,             256,  0, stream>>>(counts, totals);
    k_scantop  <<<1,                256,  0, stream>>>(totals);
    k_scanfinal<<<NBLK,             256,  0, stream>>>(counts, totals, offsets);
    k_fill     <<<NPTS / 256,       256,  0, stream>>>(voxid, offsets, order);
    k_accum    <<<NBINS / 256,      256,  0, stream>>>(counts, offsets, order, featT, out);
}